// Round 4
// baseline (4794.209 us; speedup 1.0000x reference)
//
#include <hip/hip_runtime.h>
#include <hip/hip_bf16.h>

#define T_LEN 4096

typedef __attribute__((ext_vector_type(8))) short bfrag8;
typedef __attribute__((ext_vector_type(4))) float f32x4;

// Workgroup barrier WITHOUT vmcnt(0) drain: keeps global prefetch loads in
// flight across the barrier (the __syncthreads() lowering would drain them).
__device__ __forceinline__ void wg_barrier() {
  asm volatile("s_waitcnt lgkmcnt(0)\ns_barrier" ::: "memory");
}

__device__ __forceinline__ float fact(float x, float S, float A, float B) {
  // sigmoid: S=-1/ln2, A=0, B=1 ;  tanh: S=+2/ln2, A=1, B=-2
  float e = __builtin_amdgcn_exp2f(S * x);
  return A + B * __builtin_amdgcn_rcpf(1.0f + e);
}
__device__ __forceinline__ float ftanh(float x) {
  float e = __builtin_amdgcn_exp2f(2.8853900817779268f * x);
  return 1.0f - 2.0f * __builtin_amdgcn_rcpf(1.0f + e);
}
// Broadcast lane SEL within each aligned 4-lane group (quad_perm DPP, VALU).
template <int SEL>
__device__ __forceinline__ float qb(float v) {
  union { float f; int i; } u;
  u.f = v;
  u.i = __builtin_amdgcn_mov_dpp(u.i, SEL * 0x55, 0xF, 0xF, true);
  return u.f;
}

// Load one c-row's K-fragment data for a lane: 16 fp32 (k = q*8..q*8+7 and
// 32+q*8..+7; q==3 high half is the K=60->64 zero pad). All float4 16B-aligned
// (rows are 240 B). q==3 skips the would-be-OOB load (exec-masked).
__device__ __forceinline__ void loadc(float4 (&r)[4], const float* row, int q) {
  const float* pr = row + q * 8;
  r[0] = *(const float4*)(pr);
  r[1] = *(const float4*)(pr + 4);
  r[2] = *(const float4*)(row + 32 + q * 8);
  r[3] = float4{0.f, 0.f, 0.f, 0.f};
  if (q < 3) r[3] = *(const float4*)(row + 36 + q * 8);
}

// ---------------------------------------------------------------------------
// Kernel 1: fused weights, K=128, GATE-PERMUTED for the 16-tile layout.
// ENCODER IS FOLDED IN: gates_x = x@W_ih^T with x = c@W_enc^T  ==>
//   gates_x = c @ (W_ih W_enc)^T.  W_comb[np][k<60] = sum_e W_ih[no,e]W_enc[e,k]
// (fp32 accumulate, ONE bf16 round - fewer rounding steps than the 2-stage
// path). Row layout: [0:60) comb, [60:64) zero pad, [64:128) W_hh (bf16).
// Permuted row np = tile*16 + cc: unit = tile*4 + (cc>>2), gate = cc&3,
// orig row no = gate*64 + unit.  biasc[dir][np] = b[no] + W_ih[no]·b_enc.
// ---------------------------------------------------------------------------
__global__ void prep_weights(const float* __restrict__ W_enc,
                             const float* __restrict__ b_enc,
                             const float* __restrict__ W_ih_f,
                             const float* __restrict__ W_hh_f,
                             const float* __restrict__ b_f,
                             const float* __restrict__ W_ih_b,
                             const float* __restrict__ W_hh_b,
                             const float* __restrict__ b_b,
                             __hip_bfloat16* __restrict__ Wc,
                             float* __restrict__ biasc) {
  const int dir = blockIdx.x;
  const int np = threadIdx.x;
  const int tile = np >> 4, cc = np & 15;
  const int unit = tile * 4 + (cc >> 2);
  const int gate = cc & 3;
  const int no = gate * 64 + unit;
  const float* W_ih = dir ? W_ih_b : W_ih_f;
  const float* W_hh = dir ? W_hh_b : W_hh_f;
  const float* bv = dir ? b_b : b_f;
  __hip_bfloat16* row = Wc + (size_t)(dir * 256 + np) * 128;
  for (int k = 0; k < 60; ++k) {
    float s = 0.f;
#pragma unroll
    for (int e = 0; e < 32; ++e) s += W_ih[no * 32 + e] * W_enc[e * 60 + k];
    row[k] = __float2bfloat16(s);
  }
  row[60] = row[61] = row[62] = row[63] = __float2bfloat16(0.f);
#pragma unroll
  for (int j = 0; j < 64; ++j) row[64 + j] = __float2bfloat16(W_hh[no * 64 + j]);
  float bb = bv[no];
#pragma unroll
  for (int e = 0; e < 32; ++e) bb += W_ih[no * 32 + e] * b_enc[e];
  biasc[dir * 256 + np] = bb;
}

// ---------------------------------------------------------------------------
// Kernel 2: the recurrence, reading c DIRECTLY (encoder folded into weights).
// TWO batches per WG (A-frag rows interleaved: even rows = b0, odd = b1).
// 256 WGs = 128 pairs x 2 dirs; 8 waves of 64 -> 2 waves/SIMD; each wave owns
// 2 N-tiles (32 permuted gate cols = 8 units), K=128:
//   K [0,64)   = c row fp32->bf16 (2 frags; depth-4 raw float4 prefetch,
//                stride-walked pointer, static t&3 slots)
//   K [64,128) = h from LDS ping-pong (2 x ds_read_b128, broadcast, 0-conflict)
// 8 MFMAs/wave: 2 x-chain (issue during ds_read wait) + 2 h-chain per tile.
// Per lane ONE gate value: tile = quad&1, batch = quad>>1, acc reg = batch.
// DPP gathers the 4 gates in each aligned 4-lane group; one cell chain/lane.
// ---------------------------------------------------------------------------
__global__ __launch_bounds__(512, 2) void lstm_main(
    const float* __restrict__ c, const __hip_bfloat16* __restrict__ Wc,
    const float* __restrict__ biasc, float* __restrict__ cfin) {
  __shared__ __align__(16) short Hbuf[2][2][72];  // [buf][batch parity][unit] bf16, pad 72

  const int tid = threadIdx.x, lane = tid & 63, wave = tid >> 6;
  const int quad = lane >> 4, l15 = lane & 15;
  const int g = lane & 3;
  const int tsel = quad & 1;       // which of my 2 N-tiles holds my gate col
  const int br = quad >> 1;        // which batch of the pair my lane handles
  const int unit = wave * 8 + tsel * 4 + (l15 >> 2);
  const int dir = (int)blockIdx.x & 1;
  const int pair = (int)blockIdx.x >> 1;
  const int b0 = pair * 2;
  const int bl = b0 + (l15 & 1);   // batch feeding my A-frag row

  // loop-invariant weight fragments (B-operand: lane = col, k = quad*8+j)
  bfrag8 wx[2][2], wh[2][2];
  float bias[2];
#pragma unroll
  for (int tl = 0; tl < 2; ++tl) {
    const int np = wave * 32 + tl * 16 + l15;
    const __hip_bfloat16* wr = Wc + (size_t)(dir * 256 + np) * 128 + quad * 8;
    wx[tl][0] = *(const bfrag8*)(wr);
    wx[tl][1] = *(const bfrag8*)(wr + 32);
    wh[tl][0] = *(const bfrag8*)(wr + 64);
    wh[tl][1] = *(const bfrag8*)(wr + 96);
    bias[tl] = biasc[dir * 256 + np];
  }
  // hoisted bias C-operand vectors (loop-invariant registers)
  const f32x4 bv0 = {bias[0], bias[0], bias[0], bias[0]};
  const f32x4 bv1 = {bias[1], bias[1], bias[1], bias[1]};

  // activation constants for my gate column (g==2 is the tanh gate)
  const bool isg = (g == 2);
  const float S = isg ? 2.8853900817779268f : -1.4426950408889634f;
  const float Aa = isg ? 1.0f : 0.0f;
  const float Bb = isg ? -2.0f : 1.0f;

  // c row pointer, walked by +/-1 row per step (no per-step address recompute)
  const float* p = c + ((size_t)bl * T_LEN + (dir ? (T_LEN - 1) : 0)) * 60;
  const int sstep = dir ? -60 : 60;

  // depth-4 raw fp32 prefetch (static t&3 slots; ~2000 cyc in flight)
  float4 r[4][4];
#pragma unroll
  for (int qq = 0; qq < 4; ++qq) {
    loadc(r[qq], p, quad);
    p += sstep;
  }

  // h0 = 0 for both ping-pong buffers, both parities (288 shorts total)
  if (tid < 288) ((short*)Hbuf)[tid] = 0;

  float cst = 0.f;
  wg_barrier();

#pragma unroll 4
  for (int t = 0; t < T_LEN; ++t) {
    const int cur = t & 1;
    // h A-frags: parity picked by my row's batch; addresses are 16B-aligned
    // broadcasts (8 distinct 16B lines covering 32 banks -> conflict-free).
    const short* hb = &Hbuf[cur][l15 & 1][0];
    bfrag8 ahA = *(const bfrag8*)(hb + quad * 8);       // units q*8..q*8+7
    bfrag8 ahB = *(const bfrag8*)(hb + 32 + quad * 8);  // units 32+q*8..
    // build x frags (fp32 -> bf16) from the slot loaded 4 steps ago
    union { bfrag8 v; __hip_bfloat16 h[8]; } X0, X1;
    {
      float4 q0 = r[t & 3][0], q1 = r[t & 3][1];
      float4 q2 = r[t & 3][2], q3 = r[t & 3][3];
      X0.h[0] = __float2bfloat16(q0.x); X0.h[1] = __float2bfloat16(q0.y);
      X0.h[2] = __float2bfloat16(q0.z); X0.h[3] = __float2bfloat16(q0.w);
      X0.h[4] = __float2bfloat16(q1.x); X0.h[5] = __float2bfloat16(q1.y);
      X0.h[6] = __float2bfloat16(q1.z); X0.h[7] = __float2bfloat16(q1.w);
      X1.h[0] = __float2bfloat16(q2.x); X1.h[1] = __float2bfloat16(q2.y);
      X1.h[2] = __float2bfloat16(q2.z); X1.h[3] = __float2bfloat16(q2.w);
      X1.h[4] = __float2bfloat16(q3.x); X1.h[5] = __float2bfloat16(q3.y);
      X1.h[6] = __float2bfloat16(q3.z); X1.h[7] = __float2bfloat16(q3.w);
    }
    // ---- MFMA chains: C seeded from hoisted bias vecs; x-stage (2 deep)
    //      issues while the ds_reads are in flight; h-stage 2 deep after LDS
    f32x4 a0 = __builtin_amdgcn_mfma_f32_16x16x32_bf16(X0.v, wx[0][0], bv0, 0, 0, 0);
    f32x4 a1 = __builtin_amdgcn_mfma_f32_16x16x32_bf16(X0.v, wx[1][0], bv1, 0, 0, 0);
    a0 = __builtin_amdgcn_mfma_f32_16x16x32_bf16(X1.v, wx[0][1], a0, 0, 0, 0);
    a1 = __builtin_amdgcn_mfma_f32_16x16x32_bf16(X1.v, wx[1][1], a1, 0, 0, 0);
    a0 = __builtin_amdgcn_mfma_f32_16x16x32_bf16(ahA, wh[0][0], a0, 0, 0, 0);
    a1 = __builtin_amdgcn_mfma_f32_16x16x32_bf16(ahA, wh[1][0], a1, 0, 0, 0);
    a0 = __builtin_amdgcn_mfma_f32_16x16x32_bf16(ahB, wh[0][1], a0, 0, 0, 0);
    a1 = __builtin_amdgcn_mfma_f32_16x16x32_bf16(ahB, wh[1][1], a1, 0, 0, 0);
    // prefetch c row for t+4 into the slot just consumed (wave-uniform guard;
    // loads stay in flight across the lgkm-only barrier)
    if (t < T_LEN - 4) {
      loadc(r[t & 3], p, quad);
      p += sstep;
    }
    // ---- my gate value: tile = quad&1, acc reg = batch = quad>>1 ----
    float v0 = tsel ? a1[0] : a0[0];   // batch-0 candidate
    float v1 = tsel ? a1[1] : a0[1];   // batch-1 candidate
    float v = (quad & 2) ? v1 : v0;
    float act = fact(v, S, Aa, Bb);
    // gather the 4 gates of my unit from my aligned 4-lane group (i,f,g,o)
    float gi = qb<0>(act), gf = qb<1>(act), gg = qb<2>(act), go = qb<3>(act);
    cst = gf * cst + gi * gg;
    float h = go * ftanh(cst);
    if (g == 0) *(__hip_bfloat16*)&Hbuf[cur ^ 1][br][unit] = __float2bfloat16(h);
    wg_barrier();
  }

  // reference quirk: final CELL states feed the FC
  if (g == 0) cfin[(size_t)(dir * 256 + b0 + br) * 64 + unit] = cst;
}

// ---------------------------------------------------------------------------
// Kernel 3: out[b,:] = [c_fwd(b) ; c_bwd(b)] @ W_fin^T + b_fin
// ---------------------------------------------------------------------------
__global__ void final_fc(const float* __restrict__ cfin,
                         const float* __restrict__ W_fin,
                         const float* __restrict__ b_fin,
                         float* __restrict__ out) {
  int b = threadIdx.x;  // 256 threads, 1 block
  const float* cf = cfin + (size_t)b * 64;
  const float* cb = cfin + (size_t)(256 + b) * 64;
  float a0 = b_fin[0], a1 = b_fin[1], a2 = b_fin[2];
  for (int u = 0; u < 64; ++u) {
    float vf = cf[u], vb = cb[u];
    a0 += W_fin[0 * 128 + u] * vf + W_fin[0 * 128 + 64 + u] * vb;
    a1 += W_fin[1 * 128 + u] * vf + W_fin[1 * 128 + 64 + u] * vb;
    a2 += W_fin[2 * 128 + u] * vf + W_fin[2 * 128 + 64 + u] * vb;
  }
  out[b * 3 + 0] = a0;
  out[b * 3 + 1] = a1;
  out[b * 3 + 2] = a2;
}

extern "C" void kernel_launch(void* const* d_in, const int* in_sizes, int n_in,
                              void* d_out, int out_size, void* d_ws, size_t ws_size,
                              hipStream_t stream) {
  (void)in_sizes; (void)n_in; (void)out_size; (void)ws_size;
  const float* c      = (const float*)d_in[0];
  const float* W_enc  = (const float*)d_in[1];
  const float* b_enc  = (const float*)d_in[2];
  const float* W_ih_f = (const float*)d_in[3];
  const float* W_hh_f = (const float*)d_in[4];
  const float* b_f    = (const float*)d_in[5];
  const float* W_ih_b = (const float*)d_in[6];
  const float* W_hh_b = (const float*)d_in[7];
  const float* b_b    = (const float*)d_in[8];
  const float* W_fin  = (const float*)d_in[9];
  const float* b_fin  = (const float*)d_in[10];
  float* out = (float*)d_out;

  char* ws = (char*)d_ws;
  __hip_bfloat16* Wc = (__hip_bfloat16*)ws;            // 2*256*128*2 = 131072 B
  float* biasc       = (float*)(ws + 131072);          // 2048 B
  float* cfin        = (float*)(ws + 131072 + 2048);   // 131072 B

  prep_weights<<<2, 256, 0, stream>>>(W_enc, b_enc, W_ih_f, W_hh_f, b_f,
                                      W_ih_b, W_hh_b, b_b, Wc, biasc);
  lstm_main<<<256, 512, 0, stream>>>(c, Wc, biasc, cfin);
  final_fc<<<1, 256, 0, stream>>>(cfin, W_fin, b_fin, out);
}

// Round 7
// 2328.858 us; speedup vs baseline: 2.0586x; 2.0586x over previous
//
#include <hip/hip_runtime.h>
#include <hip/hip_bf16.h>

#define T_LEN 4096

typedef __attribute__((ext_vector_type(8))) short bfrag8;
typedef __attribute__((ext_vector_type(4))) float f32x4;

// Workgroup barrier WITHOUT vmcnt(0) drain: keeps global prefetch loads in
// flight across the barrier (the __syncthreads() lowering would drain them).
__device__ __forceinline__ void wg_barrier() {
  asm volatile("s_waitcnt lgkmcnt(0)\ns_barrier" ::: "memory");
}

__device__ __forceinline__ float fact(float x, float S, float A, float B) {
  // sigmoid: S=-1/ln2, A=0, B=1 ;  tanh: S=+2/ln2, A=1, B=-2
  float e = __builtin_amdgcn_exp2f(S * x);
  return A + B * __builtin_amdgcn_rcpf(1.0f + e);
}
__device__ __forceinline__ float ftanh(float x) {
  float e = __builtin_amdgcn_exp2f(2.8853900817779268f * x);
  return 1.0f - 2.0f * __builtin_amdgcn_rcpf(1.0f + e);
}
// Broadcast lane SEL within each aligned 4-lane group (quad_perm DPP, VALU).
template <int SEL>
__device__ __forceinline__ float qb(float v) {
  union { float f; int i; } u;
  u.f = v;
  u.i = __builtin_amdgcn_mov_dpp(u.i, SEL * 0x55, 0xF, 0xF, true);
  return u.f;
}

// ---------------------------------------------------------------------------
// Kernel 1: fused weights, K=128, GATE-PERMUTED for the 16-tile layout.
// ENCODER IS FOLDED IN: gates_x = x@W_ih^T with x = c@W_enc^T  ==>
//   gates_x = c @ (W_ih W_enc)^T.  W_comb[np][k<60] = sum_e W_ih[no,e]W_enc[e,k]
// (fp32 accumulate, ONE bf16 round). Row: [0:60) comb, [60:64) pad, [64:128)
// W_hh (bf16). Permuted row np = tile*16 + cc: unit = tile*4 + (cc>>2),
// gate = cc&3, orig row no = gate*64 + unit.
// biasc[dir][np] = b[no] + W_ih[no]·b_enc.   (Proven: round-4 pass, absmax
// 0.00195 identical to the 2-stage path.)
// ---------------------------------------------------------------------------
__global__ void prep_weights(const float* __restrict__ W_enc,
                             const float* __restrict__ b_enc,
                             const float* __restrict__ W_ih_f,
                             const float* __restrict__ W_hh_f,
                             const float* __restrict__ b_f,
                             const float* __restrict__ W_ih_b,
                             const float* __restrict__ W_hh_b,
                             const float* __restrict__ b_b,
                             __hip_bfloat16* __restrict__ Wc,
                             float* __restrict__ biasc) {
  const int dir = blockIdx.x;
  const int np = threadIdx.x;
  const int tile = np >> 4, cc = np & 15;
  const int unit = tile * 4 + (cc >> 2);
  const int gate = cc & 3;
  const int no = gate * 64 + unit;
  const float* W_ih = dir ? W_ih_b : W_ih_f;
  const float* W_hh = dir ? W_hh_b : W_hh_f;
  const float* bv = dir ? b_b : b_f;
  __hip_bfloat16* row = Wc + (size_t)(dir * 256 + np) * 128;
  for (int k = 0; k < 60; ++k) {
    float s = 0.f;
#pragma unroll
    for (int e = 0; e < 32; ++e) s += W_ih[no * 32 + e] * W_enc[e * 60 + k];
    row[k] = __float2bfloat16(s);
  }
  row[60] = row[61] = row[62] = row[63] = __float2bfloat16(0.f);
#pragma unroll
  for (int j = 0; j < 64; ++j) row[64 + j] = __float2bfloat16(W_hh[no * 64 + j]);
  float bb = bv[no];
#pragma unroll
  for (int e = 0; e < 32; ++e) bb += W_ih[no * 32 + e] * b_enc[e];
  biasc[dir * 256 + np] = bb;
}

// ---------------------------------------------------------------------------
// Kernel 2: the recurrence, reading c DIRECTLY (encoder folded into weights).
// ROUND-3-PROVEN SKELETON: #pragma unroll 4 loop, [t&3] array prefetch slots,
// clamped always-load, per-step address recompute. Only deltas vs round 3:
// fp32 c loads (4 small float4 arrays instead of one bfrag8 array) + 16 cvts
// + 2 extra MFMAs (K=128 instead of 96).
// TWO batches per WG (A-frag rows interleaved: even rows = b0, odd = b1).
// 256 WGs = 128 pairs x 2 dirs; 8 waves of 64 -> 2 waves/SIMD; each wave owns
// 2 N-tiles (32 permuted gate cols = 8 units), K=128:
//   K [0,64)   = c row fp32->bf16 at consume time (depth-4 prefetch queue)
//   K [64,128) = h from LDS ping-pong (2 x ds_read_b128, broadcast, 0-conflict)
// 8 MFMAs/wave. Per lane ONE gate value: tile = quad&1, batch = quad>>1,
// acc reg = batch. DPP gathers the 4 gates per aligned 4-lane group.
// ---------------------------------------------------------------------------
__global__ __launch_bounds__(512, 2) void lstm_main(
    const float* __restrict__ c, const __hip_bfloat16* __restrict__ Wc,
    const float* __restrict__ biasc, float* __restrict__ cfin) {
  __shared__ __align__(16) short Hbuf[2][2][72];  // [buf][batch parity][unit] bf16, pad 72

  const int tid = threadIdx.x, lane = tid & 63, wave = tid >> 6;
  const int quad = lane >> 4, l15 = lane & 15;
  const int g = lane & 3;
  const int tsel = quad & 1;       // which of my 2 N-tiles holds my gate col
  const int br = quad >> 1;        // which batch of the pair my lane handles
  const int unit = wave * 8 + tsel * 4 + (l15 >> 2);
  const int dir = (int)blockIdx.x & 1;
  const int pair = (int)blockIdx.x >> 1;
  const int b0 = pair * 2;
  const int bl = b0 + (l15 & 1);   // batch feeding my A-frag row

  // loop-invariant weight fragments (B-operand: lane = col, k = quad*8+j)
  bfrag8 wx[2][2], wh[2][2];
  float bias[2];
#pragma unroll
  for (int tl = 0; tl < 2; ++tl) {
    const int np = wave * 32 + tl * 16 + l15;
    const __hip_bfloat16* wr = Wc + (size_t)(dir * 256 + np) * 128 + quad * 8;
    wx[tl][0] = *(const bfrag8*)(wr);
    wx[tl][1] = *(const bfrag8*)(wr + 32);
    wh[tl][0] = *(const bfrag8*)(wr + 64);
    wh[tl][1] = *(const bfrag8*)(wr + 96);
    bias[tl] = biasc[dir * 256 + np];
  }
  // hoisted bias C-operand vectors (loop-invariant registers)
  const f32x4 bv0 = {bias[0], bias[0], bias[0], bias[0]};
  const f32x4 bv1 = {bias[1], bias[1], bias[1], bias[1]};

  // activation constants for my gate column (g==2 is the tanh gate)
  const bool isg = (g == 2);
  const float S = isg ? 2.8853900817779268f : -1.4426950408889634f;
  const float Aa = isg ? 1.0f : 0.0f;
  const float Bb = isg ? -2.0f : 1.0f;

  const float* cb = c + (size_t)bl * T_LEN * 60;  // my batch's c rows (240 B)

  // fp32 prefetch queue: FOUR independent 4-slot float4 arrays indexed [t&3]
  // under #pragma unroll 4 -> static indices -> VGPRs (round-3-proven shape;
  // the single [4][4] array was LDS-promoted = round-4 disaster).
  // Lane's 16 c-floats: k = quad*8..+7 (pfa,pfb), 32+quad*8..+7 (pfc,pfd);
  // quad==3 pfd is the K=60->64 zero pad (ternary pattern proven in encoder).
  float4 pfa[4], pfb[4], pfc[4], pfd[4];
#pragma unroll
  for (int qq = 0; qq < 4; ++qq) {  // prefetch rows for t = 0..3
    int tp = dir ? (T_LEN - 1 - qq) : qq;
    const float* rr = cb + (size_t)tp * 60;
    pfa[qq] = *(const float4*)(rr + quad * 8);
    pfb[qq] = *(const float4*)(rr + quad * 8 + 4);
    pfc[qq] = *(const float4*)(rr + 32 + quad * 8);
    pfd[qq] = (quad == 3) ? float4{0.f, 0.f, 0.f, 0.f}
                          : *(const float4*)(rr + 36 + quad * 8);
  }

  // h0 = 0 for both ping-pong buffers, both parities (288 shorts total)
  if (tid < 288) ((short*)Hbuf)[tid] = 0;

  float cst = 0.f;
  wg_barrier();

#pragma unroll 4
  for (int t = 0; t < T_LEN; ++t) {
    const int cur = t & 1;
    // h A-frags: parity picked by my row's batch; addresses are 16B-aligned
    // broadcasts (8 distinct 16B lines covering 32 banks -> conflict-free).
    const short* hb = &Hbuf[cur][l15 & 1][0];
    bfrag8 ahA = *(const bfrag8*)(hb + quad * 8);       // units q*8..q*8+7
    bfrag8 ahB = *(const bfrag8*)(hb + 32 + quad * 8);  // units 32+q*8..
    // build x frags (fp32 -> bf16) from the slot loaded 4 steps ago
    union { bfrag8 v; __hip_bfloat16 h[8]; } X0, X1;
    {
      float4 f0 = pfa[t & 3], f1 = pfb[t & 3];
      float4 f2 = pfc[t & 3], f3 = pfd[t & 3];
      X0.h[0] = __float2bfloat16(f0.x); X0.h[1] = __float2bfloat16(f0.y);
      X0.h[2] = __float2bfloat16(f0.z); X0.h[3] = __float2bfloat16(f0.w);
      X0.h[4] = __float2bfloat16(f1.x); X0.h[5] = __float2bfloat16(f1.y);
      X0.h[6] = __float2bfloat16(f1.z); X0.h[7] = __float2bfloat16(f1.w);
      X1.h[0] = __float2bfloat16(f2.x); X1.h[1] = __float2bfloat16(f2.y);
      X1.h[2] = __float2bfloat16(f2.z); X1.h[3] = __float2bfloat16(f2.w);
      X1.h[4] = __float2bfloat16(f3.x); X1.h[5] = __float2bfloat16(f3.y);
      X1.h[6] = __float2bfloat16(f3.z); X1.h[7] = __float2bfloat16(f3.w);
    }
    // ---- MFMA chains: C seeded from hoisted bias vecs; x-stage (2 deep)
    //      issues while the ds_reads are in flight; h-stage 2 deep after LDS
    f32x4 a0 = __builtin_amdgcn_mfma_f32_16x16x32_bf16(X0.v, wx[0][0], bv0, 0, 0, 0);
    f32x4 a1 = __builtin_amdgcn_mfma_f32_16x16x32_bf16(X0.v, wx[1][0], bv1, 0, 0, 0);
    a0 = __builtin_amdgcn_mfma_f32_16x16x32_bf16(X1.v, wx[0][1], a0, 0, 0, 0);
    a1 = __builtin_amdgcn_mfma_f32_16x16x32_bf16(X1.v, wx[1][1], a1, 0, 0, 0);
    a0 = __builtin_amdgcn_mfma_f32_16x16x32_bf16(ahA, wh[0][0], a0, 0, 0, 0);
    a1 = __builtin_amdgcn_mfma_f32_16x16x32_bf16(ahA, wh[1][0], a1, 0, 0, 0);
    a0 = __builtin_amdgcn_mfma_f32_16x16x32_bf16(ahB, wh[0][1], a0, 0, 0, 0);
    a1 = __builtin_amdgcn_mfma_f32_16x16x32_bf16(ahB, wh[1][1], a1, 0, 0, 0);
    {  // prefetch c row for t+4 (CLAMPED always-load, round-3-proven; loads
       // stay in flight across the lgkm-only barrier)
      int tn = t + 4; if (tn > T_LEN - 1) tn = T_LEN - 1;
      int tp = dir ? (T_LEN - 1 - tn) : tn;
      const float* rr = cb + (size_t)tp * 60;
      pfa[t & 3] = *(const float4*)(rr + quad * 8);
      pfb[t & 3] = *(const float4*)(rr + quad * 8 + 4);
      pfc[t & 3] = *(const float4*)(rr + 32 + quad * 8);
      pfd[t & 3] = (quad == 3) ? float4{0.f, 0.f, 0.f, 0.f}
                               : *(const float4*)(rr + 36 + quad * 8);
    }
    // ---- my gate value: tile = quad&1, acc reg = batch = quad>>1 ----
    float v0 = tsel ? a1[0] : a0[0];   // batch-0 candidate
    float v1 = tsel ? a1[1] : a0[1];   // batch-1 candidate
    float v = (quad & 2) ? v1 : v0;
    float act = fact(v, S, Aa, Bb);
    // gather the 4 gates of my unit from my aligned 4-lane group (i,f,g,o)
    float gi = qb<0>(act), gf = qb<1>(act), gg = qb<2>(act), go = qb<3>(act);
    cst = gf * cst + gi * gg;
    float h = go * ftanh(cst);
    if (g == 0) *(__hip_bfloat16*)&Hbuf[cur ^ 1][br][unit] = __float2bfloat16(h);
    wg_barrier();
  }

  // reference quirk: final CELL states feed the FC
  if (g == 0) cfin[(size_t)(dir * 256 + b0 + br) * 64 + unit] = cst;
}

// ---------------------------------------------------------------------------
// Kernel 3: out[b,:] = [c_fwd(b) ; c_bwd(b)] @ W_fin^T + b_fin
// ---------------------------------------------------------------------------
__global__ void final_fc(const float* __restrict__ cfin,
                         const float* __restrict__ W_fin,
                         const float* __restrict__ b_fin,
                         float* __restrict__ out) {
  int b = threadIdx.x;  // 256 threads, 1 block
  const float* cf = cfin + (size_t)b * 64;
  const float* cb = cfin + (size_t)(256 + b) * 64;
  float a0 = b_fin[0], a1 = b_fin[1], a2 = b_fin[2];
  for (int u = 0; u < 64; ++u) {
    float vf = cf[u], vb = cb[u];
    a0 += W_fin[0 * 128 + u] * vf + W_fin[0 * 128 + 64 + u] * vb;
    a1 += W_fin[1 * 128 + u] * vf + W_fin[1 * 128 + 64 + u] * vb;
    a2 += W_fin[2 * 128 + u] * vf + W_fin[2 * 128 + 64 + u] * vb;
  }
  out[b * 3 + 0] = a0;
  out[b * 3 + 1] = a1;
  out[b * 3 + 2] = a2;
}

extern "C" void kernel_launch(void* const* d_in, const int* in_sizes, int n_in,
                              void* d_out, int out_size, void* d_ws, size_t ws_size,
                              hipStream_t stream) {
  (void)in_sizes; (void)n_in; (void)out_size; (void)ws_size;
  const float* c      = (const float*)d_in[0];
  const float* W_enc  = (const float*)d_in[1];
  const float* b_enc  = (const float*)d_in[2];
  const float* W_ih_f = (const float*)d_in[3];
  const float* W_hh_f = (const float*)d_in[4];
  const float* b_f    = (const float*)d_in[5];
  const float* W_ih_b = (const float*)d_in[6];
  const float* W_hh_b = (const float*)d_in[7];
  const float* b_b    = (const float*)d_in[8];
  const float* W_fin  = (const float*)d_in[9];
  const float* b_fin  = (const float*)d_in[10];
  float* out = (float*)d_out;

  char* ws = (char*)d_ws;
  __hip_bfloat16* Wc = (__hip_bfloat16*)ws;            // 2*256*128*2 = 131072 B
  float* biasc       = (float*)(ws + 131072);          // 2048 B
  float* cfin        = (float*)(ws + 131072 + 2048);   // 131072 B

  prep_weights<<<2, 256, 0, stream>>>(W_enc, b_enc, W_ih_f, W_hh_f, b_f,
                                      W_ih_b, W_hh_b, b_b, Wc, biasc);
  lstm_main<<<256, 512, 0, stream>>>(c, Wc, biasc, cfin);
  final_fc<<<1, 256, 0, stream>>>(cfin, W_fin, b_fin, out);
}

// Round 8
// 1322.413 us; speedup vs baseline: 3.6253x; 1.7611x over previous
//
#include <hip/hip_runtime.h>
#include <hip/hip_bf16.h>

#define T_LEN 4096

typedef __attribute__((ext_vector_type(8))) short bfrag8;
typedef __attribute__((ext_vector_type(4))) float f32x4;

// Workgroup barrier WITHOUT vmcnt(0) drain: keeps global prefetch loads in
// flight across the barrier (the __syncthreads() lowering would drain them).
__device__ __forceinline__ void wg_barrier() {
  asm volatile("s_waitcnt lgkmcnt(0)\ns_barrier" ::: "memory");
}

__device__ __forceinline__ float fact(float x, float S, float A, float B) {
  // sigmoid: S=-1/ln2, A=0, B=1 ;  tanh: S=+2/ln2, A=1, B=-2
  float e = __builtin_amdgcn_exp2f(S * x);
  return A + B * __builtin_amdgcn_rcpf(1.0f + e);
}
__device__ __forceinline__ float ftanh(float x) {
  float e = __builtin_amdgcn_exp2f(2.8853900817779268f * x);
  return 1.0f - 2.0f * __builtin_amdgcn_rcpf(1.0f + e);
}
// Broadcast lane SEL within each aligned 4-lane group (quad_perm DPP, VALU).
template <int SEL>
__device__ __forceinline__ float qb(float v) {
  union { float f; int i; } u;
  u.f = v;
  u.i = __builtin_amdgcn_mov_dpp(u.i, SEL * 0x55, 0xF, 0xF, true);
  return u.f;
}

// ---------------------------------------------------------------------------
// Kernel 0: bf16 copy of W_enc padded to K=64 (B-operand for the encoder).
// ---------------------------------------------------------------------------
__global__ void prep_enc(const float* __restrict__ W_enc,
                         __hip_bfloat16* __restrict__ Wencb) {
  int u = threadIdx.x;
  if (u < 32) {
    for (int k = 0; k < 64; ++k)
      Wencb[u * 64 + k] = __float2bfloat16(k < 60 ? W_enc[u * 60 + k] : 0.0f);
  }
}

// ---------------------------------------------------------------------------
// Kernel 1: MFMA encoder  x[row][u] = sum_k c[row][k] * W_enc[u][k]  (bf16).
// One wave per 16 rows: A = c (fp32->bf16 inline, K=60 pad 64), B = Wencb,
// 2 N-tiles (u 0-15, 16-31) x 2 K-tiles = 4 MFMAs. b_enc folded into LSTM bias.
// Memory-bound: 251 MB read + 64 MB write.
// ---------------------------------------------------------------------------
__global__ __launch_bounds__(256) void encoder(const float* __restrict__ c,
                                               const __hip_bfloat16* __restrict__ Wencb,
                                               __hip_bfloat16* __restrict__ x) {
  const int lane = threadIdx.x & 63, wave = threadIdx.x >> 6;
  const int q = lane >> 4, l15 = lane & 15;
  const size_t r0 = ((size_t)blockIdx.x * 4 + wave) * 16;

  bfrag8 bf00 = *(const bfrag8*)(Wencb + (0 * 16 + l15) * 64 + 0 * 32 + q * 8);
  bfrag8 bf01 = *(const bfrag8*)(Wencb + (0 * 16 + l15) * 64 + 1 * 32 + q * 8);
  bfrag8 bf10 = *(const bfrag8*)(Wencb + (1 * 16 + l15) * 64 + 0 * 32 + q * 8);
  bfrag8 bf11 = *(const bfrag8*)(Wencb + (1 * 16 + l15) * 64 + 1 * 32 + q * 8);

  const float* cr = c + (r0 + l15) * 60;   // A row = l15
  float4 a0 = *(const float4*)(cr + q * 8);          // k = q*8 .. +3
  float4 a1 = *(const float4*)(cr + q * 8 + 4);      // k = q*8+4 .. +7
  float4 a2 = *(const float4*)(cr + 32 + q * 8);     // k = 32+q*8 (q=3: 56-59)
  float4 a3 = (q == 3) ? float4{0.f, 0.f, 0.f, 0.f}  // k 60-63 pad
                       : *(const float4*)(cr + 36 + q * 8);
  union { bfrag8 v; __hip_bfloat16 h[8]; } A0, A1;
  A0.h[0] = __float2bfloat16(a0.x); A0.h[1] = __float2bfloat16(a0.y);
  A0.h[2] = __float2bfloat16(a0.z); A0.h[3] = __float2bfloat16(a0.w);
  A0.h[4] = __float2bfloat16(a1.x); A0.h[5] = __float2bfloat16(a1.y);
  A0.h[6] = __float2bfloat16(a1.z); A0.h[7] = __float2bfloat16(a1.w);
  A1.h[0] = __float2bfloat16(a2.x); A1.h[1] = __float2bfloat16(a2.y);
  A1.h[2] = __float2bfloat16(a2.z); A1.h[3] = __float2bfloat16(a2.w);
  A1.h[4] = __float2bfloat16(a3.x); A1.h[5] = __float2bfloat16(a3.y);
  A1.h[6] = __float2bfloat16(a3.z); A1.h[7] = __float2bfloat16(a3.w);

  f32x4 acc0 = {0.f, 0.f, 0.f, 0.f}, acc1 = {0.f, 0.f, 0.f, 0.f};
  acc0 = __builtin_amdgcn_mfma_f32_16x16x32_bf16(A0.v, bf00, acc0, 0, 0, 0);
  acc1 = __builtin_amdgcn_mfma_f32_16x16x32_bf16(A0.v, bf10, acc1, 0, 0, 0);
  acc0 = __builtin_amdgcn_mfma_f32_16x16x32_bf16(A1.v, bf01, acc0, 0, 0, 0);
  acc1 = __builtin_amdgcn_mfma_f32_16x16x32_bf16(A1.v, bf11, acc1, 0, 0, 0);

#pragma unroll
  for (int r = 0; r < 4; ++r) {  // D: col = l15, row = q*4 + r
    size_t row = r0 + q * 4 + r;
    x[row * 32 + l15]      = __float2bfloat16(acc0[r]);
    x[row * 32 + 16 + l15] = __float2bfloat16(acc1[r]);
  }
}

// ---------------------------------------------------------------------------
// Kernel 2: fused LSTM weights, K=96, GATE-PERMUTED for the 16-tile layout.
// Permuted row np = tile*16 + c  (tile=np>>4 in [0,16), c=np&15):
//   unit = tile*4 + (c>>2), gate = c&3, orig row no = gate*64 + unit.
// Wc[dir][np][0:32) = W_ih, [32:96) = W_hh (bf16).
// biasc[dir][np] = b[no] + W_ih[no]·b_enc  (fp32).
// ---------------------------------------------------------------------------
__global__ void prep_weights(const float* __restrict__ b_enc,
                             const float* __restrict__ W_ih_f,
                             const float* __restrict__ W_hh_f,
                             const float* __restrict__ b_f,
                             const float* __restrict__ W_ih_b,
                             const float* __restrict__ W_hh_b,
                             const float* __restrict__ b_b,
                             __hip_bfloat16* __restrict__ Wc,
                             float* __restrict__ biasc) {
  const int dir = blockIdx.x;
  const int np = threadIdx.x;
  const int tile = np >> 4, cc = np & 15;
  const int unit = tile * 4 + (cc >> 2);
  const int gate = cc & 3;
  const int no = gate * 64 + unit;
  const float* W_ih = dir ? W_ih_b : W_ih_f;
  const float* W_hh = dir ? W_hh_b : W_hh_f;
  const float* bv = dir ? b_b : b_f;
  __hip_bfloat16* row = Wc + (size_t)(dir * 256 + np) * 96;
#pragma unroll
  for (int k = 0; k < 32; ++k) row[k] = __float2bfloat16(W_ih[no * 32 + k]);
#pragma unroll
  for (int j = 0; j < 64; ++j) row[32 + j] = __float2bfloat16(W_hh[no * 64 + j]);
  float bb = bv[no];
#pragma unroll
  for (int e = 0; e < 32; ++e) bb += W_ih[no * 32 + e] * b_enc[e];
  biasc[dir * 256 + np] = bb;
}

// ---------------------------------------------------------------------------
// Kernel 3: the recurrence. TWO batches per WG (A-frag rows interleaved:
// even rows = b0, odd rows = b1). 256 WGs = 128 pairs x 2 dirs.
// EIGHT waves of 64 (512 thr) -> 2 waves per SIMD: each wave owns 2 N-tiles
// (32 permuted gate cols = 8 units) x K=96 = 6 MFMAs. Per SIMD the MFMA load
// is unchanged (2x6), but each wave's dependency stalls (ds_read, MFMA->
// epilogue wait, exp2/rcp latency) are filled by the other wave's issue.
// Per lane: ONE gate value. quad encodes (tile = quad&1, batch = quad>>1);
// acc reg r = batch r (rows interleaved, quad*4 even). DPP gathers the 4
// gates within each aligned 4-lane group; each lane runs one cell chain.
// ---------------------------------------------------------------------------
__global__ __launch_bounds__(512, 2) void lstm_main(
    const __hip_bfloat16* __restrict__ x, const __hip_bfloat16* __restrict__ Wc,
    const float* __restrict__ biasc, float* __restrict__ cfin) {
  __shared__ __align__(16) short Hbuf[2][2][72];  // [buf][batch parity][unit] bf16, pad 72

  const int tid = threadIdx.x, lane = tid & 63, wave = tid >> 6;
  const int quad = lane >> 4, l15 = lane & 15;
  const int g = lane & 3;
  const int tsel = quad & 1;       // which of my 2 N-tiles holds my gate col
  const int br = quad >> 1;        // which batch of the pair my lane handles
  const int unit = wave * 8 + tsel * 4 + (l15 >> 2);
  const int dir = (int)blockIdx.x & 1;
  const int pair = (int)blockIdx.x >> 1;
  const int b0 = pair * 2;
  const int bl = b0 + (l15 & 1);   // batch feeding my A-frag row

  // loop-invariant weight fragments (B-operand: lane = col, k = quad*8+j)
  bfrag8 wf[2][3];
  float bias[2];
#pragma unroll
  for (int tl = 0; tl < 2; ++tl) {
    const int np = wave * 32 + tl * 16 + l15;
    const __hip_bfloat16* wr = Wc + (size_t)(dir * 256 + np) * 96 + quad * 8;
#pragma unroll
    for (int kt = 0; kt < 3; ++kt) wf[tl][kt] = *(const bfrag8*)(wr + kt * 32);
    bias[tl] = biasc[dir * 256 + np];
  }
  // hoisted bias C-operand vectors (loop-invariant registers)
  const f32x4 bv0 = {bias[0], bias[0], bias[0], bias[0]};
  const f32x4 bv1 = {bias[1], bias[1], bias[1], bias[1]};

  // activation constants for my gate column (g==2 is the tanh gate)
  const bool isg = (g == 2);
  const float S = isg ? 2.8853900817779268f : -1.4426950408889634f;
  const float Aa = isg ? 1.0f : 0.0f;
  const float Bb = isg ? -2.0f : 1.0f;

  const __hip_bfloat16* xr = x + (size_t)bl * T_LEN * 32 + quad * 8;

  // h0 = 0 for both ping-pong buffers, both parities (288 shorts total)
  if (tid < 288) ((short*)Hbuf)[tid] = 0;

  bfrag8 xb[4];
#pragma unroll
  for (int qq = 0; qq < 4; ++qq) {  // prefetch x frags for t = 0..3
    int tp = dir ? (T_LEN - 1 - qq) : qq;
    xb[qq] = *(const bfrag8*)(xr + (size_t)tp * 32);
  }

  float cst = 0.f;
  wg_barrier();

#pragma unroll 4
  for (int t = 0; t < T_LEN; ++t) {
    const int cur = t & 1;
    // h A-frags: parity picked by my row's batch; addresses are 16B-aligned
    // broadcasts (8 distinct 16B lines covering 32 banks -> conflict-free).
    const short* hb = &Hbuf[cur][l15 & 1][0];
    bfrag8 ahA = *(const bfrag8*)(hb + quad * 8);       // units q*8..q*8+7
    bfrag8 ahB = *(const bfrag8*)(hb + 32 + quad * 8);  // units 32+q*8..
    // ---- MFMA chains: C seeded from hoisted bias vecs; x-stage issues
    //      while the ds_reads are in flight; h-stage is 2-deep after LDS ----
    f32x4 a0 = __builtin_amdgcn_mfma_f32_16x16x32_bf16(xb[t & 3], wf[0][0], bv0, 0, 0, 0);
    f32x4 a1 = __builtin_amdgcn_mfma_f32_16x16x32_bf16(xb[t & 3], wf[1][0], bv1, 0, 0, 0);
    a0 = __builtin_amdgcn_mfma_f32_16x16x32_bf16(ahA, wf[0][1], a0, 0, 0, 0);
    a1 = __builtin_amdgcn_mfma_f32_16x16x32_bf16(ahA, wf[1][1], a1, 0, 0, 0);
    a0 = __builtin_amdgcn_mfma_f32_16x16x32_bf16(ahB, wf[0][2], a0, 0, 0, 0);
    a1 = __builtin_amdgcn_mfma_f32_16x16x32_bf16(ahB, wf[1][2], a1, 0, 0, 0);
    {  // prefetch x frag for t+4 (stays in flight across the lgkm barrier)
      int tn = t + 4; if (tn > T_LEN - 1) tn = T_LEN - 1;
      int tp = dir ? (T_LEN - 1 - tn) : tn;
      xb[t & 3] = *(const bfrag8*)(xr + (size_t)tp * 32);
    }
    // ---- my gate value: tile = quad&1, acc reg = batch = quad>>1 ----
    float v0 = tsel ? a1[0] : a0[0];   // batch-0 candidate
    float v1 = tsel ? a1[1] : a0[1];   // batch-1 candidate
    float v = (quad & 2) ? v1 : v0;
    float act = fact(v, S, Aa, Bb);
    // gather the 4 gates of my unit from my aligned 4-lane group (i,f,g,o)
    float gi = qb<0>(act), gf = qb<1>(act), gg = qb<2>(act), go = qb<3>(act);
    cst = gf * cst + gi * gg;
    float h = go * ftanh(cst);
    if (g == 0) *(__hip_bfloat16*)&Hbuf[cur ^ 1][br][unit] = __float2bfloat16(h);
    wg_barrier();
  }

  // reference quirk: final CELL states feed the FC
  if (g == 0) cfin[(size_t)(dir * 256 + b0 + br) * 64 + unit] = cst;
}

// ---------------------------------------------------------------------------
// Kernel 4: out[b,:] = [c_fwd(b) ; c_bwd(b)] @ W_fin^T + b_fin
// ---------------------------------------------------------------------------
__global__ void final_fc(const float* __restrict__ cfin,
                         const float* __restrict__ W_fin,
                         const float* __restrict__ b_fin,
                         float* __restrict__ out) {
  int b = threadIdx.x;  // 256 threads, 1 block
  const float* cf = cfin + (size_t)b * 64;
  const float* cb = cfin + (size_t)(256 + b) * 64;
  float a0 = b_fin[0], a1 = b_fin[1], a2 = b_fin[2];
  for (int u = 0; u < 64; ++u) {
    float vf = cf[u], vb = cb[u];
    a0 += W_fin[0 * 128 + u] * vf + W_fin[0 * 128 + 64 + u] * vb;
    a1 += W_fin[1 * 128 + u] * vf + W_fin[1 * 128 + 64 + u] * vb;
    a2 += W_fin[2 * 128 + u] * vf + W_fin[2 * 128 + 64 + u] * vb;
  }
  out[b * 3 + 0] = a0;
  out[b * 3 + 1] = a1;
  out[b * 3 + 2] = a2;
}

extern "C" void kernel_launch(void* const* d_in, const int* in_sizes, int n_in,
                              void* d_out, int out_size, void* d_ws, size_t ws_size,
                              hipStream_t stream) {
  (void)in_sizes; (void)n_in; (void)out_size; (void)ws_size;
  const float* c      = (const float*)d_in[0];
  const float* W_enc  = (const float*)d_in[1];
  const float* b_enc  = (const float*)d_in[2];
  const float* W_ih_f = (const float*)d_in[3];
  const float* W_hh_f = (const float*)d_in[4];
  const float* b_f    = (const float*)d_in[5];
  const float* W_ih_b = (const float*)d_in[6];
  const float* W_hh_b = (const float*)d_in[7];
  const float* b_b    = (const float*)d_in[8];
  const float* W_fin  = (const float*)d_in[9];
  const float* b_fin  = (const float*)d_in[10];
  float* out = (float*)d_out;

  char* ws = (char*)d_ws;
  __hip_bfloat16* x     = (__hip_bfloat16*)ws;                      // 64 MiB
  __hip_bfloat16* Wc    = (__hip_bfloat16*)(ws + 67108864);         // 98304 B
  float* biasc          = (float*)(ws + 67108864 + 98304);          // 2048 B
  __hip_bfloat16* Wencb = (__hip_bfloat16*)(ws + 67108864 + 100352); // 4096 B
  float* cfin           = (float*)(ws + 67108864 + 104448);         // 131072 B

  prep_enc<<<1, 32, 0, stream>>>(W_enc, Wencb);
  prep_weights<<<2, 256, 0, stream>>>(b_enc, W_ih_f, W_hh_f, b_f,
                                      W_ih_b, W_hh_b, b_b, Wc, biasc);
  encoder<<<16384, 256, 0, stream>>>(c, Wencb, x);
  lstm_main<<<256, 512, 0, stream>>>(x, Wc, biasc, cfin);
  final_fc<<<1, 256, 0, stream>>>(cfin, W_fin, b_fin, out);
}

// Round 9
// 1312.347 us; speedup vs baseline: 3.6532x; 1.0077x over previous
//
#include <hip/hip_runtime.h>
#include <hip/hip_bf16.h>

#define T_LEN 4096

typedef __attribute__((ext_vector_type(8))) short bfrag8;
typedef __attribute__((ext_vector_type(4))) float f32x4;

// Workgroup barrier WITHOUT vmcnt(0) drain: keeps global prefetch loads in
// flight across the barrier (the __syncthreads() lowering would drain them).
__device__ __forceinline__ void wg_barrier() {
  asm volatile("s_waitcnt lgkmcnt(0)\ns_barrier" ::: "memory");
}

__device__ __forceinline__ float fact(float x, float S, float A, float B) {
  // sigmoid: S=-1/ln2, A=0, B=1 ;  tanh: S=+2/ln2, A=1, B=-2
  float e = __builtin_amdgcn_exp2f(S * x);
  return A + B * __builtin_amdgcn_rcpf(1.0f + e);
}
__device__ __forceinline__ float ftanh(float x) {
  float e = __builtin_amdgcn_exp2f(2.8853900817779268f * x);
  return 1.0f - 2.0f * __builtin_amdgcn_rcpf(1.0f + e);
}
// Broadcast lane SEL within each aligned 4-lane group (quad_perm DPP, VALU).
template <int SEL>
__device__ __forceinline__ float qb(float v) {
  union { float f; int i; } u;
  u.f = v;
  u.i = __builtin_amdgcn_mov_dpp(u.i, SEL * 0x55, 0xF, 0xF, true);
  return u.f;
}

// ---------------------------------------------------------------------------
// Kernel 1: MFMA encoder  x[row][u] = sum_k c[row][k] * W_enc[u][k]  (bf16).
// prep_enc FOLDED IN: each block stages bf16 W_enc (padded to K=64) in LDS
// (4 KB; redundant fp32 W_enc reads are L2-cached). One wave per 16 rows:
// A = c (fp32->bf16 inline), B = W_enc from LDS, 2 N-tiles x 2 K-tiles =
// 4 MFMAs. b_enc folded into LSTM bias. Memory-bound: 251 MB read + 64 MB wr.
// ---------------------------------------------------------------------------
__global__ __launch_bounds__(256) void encoder(const float* __restrict__ c,
                                               const float* __restrict__ W_enc,
                                               __hip_bfloat16* __restrict__ x) {
  __shared__ __align__(16) __hip_bfloat16 Wl[32 * 64];
  {
    const int i0 = threadIdx.x * 8;       // 256 thr x 8 = 2048 elements
    const int u = i0 >> 6, k0 = i0 & 63;  // k0 multiple of 8, no row crossing
#pragma unroll
    for (int j = 0; j < 8; ++j) {
      int kk = k0 + j;
      Wl[i0 + j] = __float2bfloat16(kk < 60 ? W_enc[u * 60 + kk] : 0.0f);
    }
  }
  __syncthreads();

  const int lane = threadIdx.x & 63, wave = threadIdx.x >> 6;
  const int q = lane >> 4, l15 = lane & 15;
  const size_t r0 = ((size_t)blockIdx.x * 4 + wave) * 16;

  const float* cr = c + (r0 + l15) * 60;   // A row = l15
  float4 a0 = *(const float4*)(cr + q * 8);          // k = q*8 .. +3
  float4 a1 = *(const float4*)(cr + q * 8 + 4);      // k = q*8+4 .. +7
  float4 a2 = *(const float4*)(cr + 32 + q * 8);     // k = 32+q*8 (q=3: 56-59)
  float4 a3 = (q == 3) ? float4{0.f, 0.f, 0.f, 0.f}  // k 60-63 pad
                       : *(const float4*)(cr + 36 + q * 8);

  bfrag8 bf00 = *(const bfrag8*)(Wl + (0 * 16 + l15) * 64 + 0 * 32 + q * 8);
  bfrag8 bf01 = *(const bfrag8*)(Wl + (0 * 16 + l15) * 64 + 1 * 32 + q * 8);
  bfrag8 bf10 = *(const bfrag8*)(Wl + (1 * 16 + l15) * 64 + 0 * 32 + q * 8);
  bfrag8 bf11 = *(const bfrag8*)(Wl + (1 * 16 + l15) * 64 + 1 * 32 + q * 8);

  union { bfrag8 v; __hip_bfloat16 h[8]; } A0, A1;
  A0.h[0] = __float2bfloat16(a0.x); A0.h[1] = __float2bfloat16(a0.y);
  A0.h[2] = __float2bfloat16(a0.z); A0.h[3] = __float2bfloat16(a0.w);
  A0.h[4] = __float2bfloat16(a1.x); A0.h[5] = __float2bfloat16(a1.y);
  A0.h[6] = __float2bfloat16(a1.z); A0.h[7] = __float2bfloat16(a1.w);
  A1.h[0] = __float2bfloat16(a2.x); A1.h[1] = __float2bfloat16(a2.y);
  A1.h[2] = __float2bfloat16(a2.z); A1.h[3] = __float2bfloat16(a2.w);
  A1.h[4] = __float2bfloat16(a3.x); A1.h[5] = __float2bfloat16(a3.y);
  A1.h[6] = __float2bfloat16(a3.z); A1.h[7] = __float2bfloat16(a3.w);

  f32x4 acc0 = {0.f, 0.f, 0.f, 0.f}, acc1 = {0.f, 0.f, 0.f, 0.f};
  acc0 = __builtin_amdgcn_mfma_f32_16x16x32_bf16(A0.v, bf00, acc0, 0, 0, 0);
  acc1 = __builtin_amdgcn_mfma_f32_16x16x32_bf16(A0.v, bf10, acc1, 0, 0, 0);
  acc0 = __builtin_amdgcn_mfma_f32_16x16x32_bf16(A1.v, bf01, acc0, 0, 0, 0);
  acc1 = __builtin_amdgcn_mfma_f32_16x16x32_bf16(A1.v, bf11, acc1, 0, 0, 0);

#pragma unroll
  for (int r = 0; r < 4; ++r) {  // D: col = l15, row = q*4 + r
    size_t row = r0 + q * 4 + r;
    x[row * 32 + l15]      = __float2bfloat16(acc0[r]);
    x[row * 32 + 16 + l15] = __float2bfloat16(acc1[r]);
  }
}

// ---------------------------------------------------------------------------
// Kernel 2: fused LSTM weights, K=96, GATE-PERMUTED for the 16-tile layout.
// Permuted row np = tile*16 + c  (tile=np>>4 in [0,16), c=np&15):
//   unit = tile*4 + (c>>2), gate = c&3, orig row no = gate*64 + unit.
// Wc[dir][np][0:32) = W_ih, [32:96) = W_hh (bf16).
// biasc[dir][np] = b[no] + W_ih[no]·b_enc  (fp32).
// ---------------------------------------------------------------------------
__global__ void prep_weights(const float* __restrict__ b_enc,
                             const float* __restrict__ W_ih_f,
                             const float* __restrict__ W_hh_f,
                             const float* __restrict__ b_f,
                             const float* __restrict__ W_ih_b,
                             const float* __restrict__ W_hh_b,
                             const float* __restrict__ b_b,
                             __hip_bfloat16* __restrict__ Wc,
                             float* __restrict__ biasc) {
  const int dir = blockIdx.x;
  const int np = threadIdx.x;
  const int tile = np >> 4, cc = np & 15;
  const int unit = tile * 4 + (cc >> 2);
  const int gate = cc & 3;
  const int no = gate * 64 + unit;
  const float* W_ih = dir ? W_ih_b : W_ih_f;
  const float* W_hh = dir ? W_hh_b : W_hh_f;
  const float* bv = dir ? b_b : b_f;
  __hip_bfloat16* row = Wc + (size_t)(dir * 256 + np) * 96;
#pragma unroll
  for (int k = 0; k < 32; ++k) row[k] = __float2bfloat16(W_ih[no * 32 + k]);
#pragma unroll
  for (int j = 0; j < 64; ++j) row[32 + j] = __float2bfloat16(W_hh[no * 64 + j]);
  float bb = bv[no];
#pragma unroll
  for (int e = 0; e < 32; ++e) bb += W_ih[no * 32 + e] * b_enc[e];
  biasc[dir * 256 + np] = bb;
}

// ---------------------------------------------------------------------------
// Kernel 3: the recurrence. TWO batches per WG (A-frag rows interleaved:
// even rows = b0, odd rows = b1). 256 WGs = 128 pairs x 2 dirs.
// EIGHT waves of 64 (512 thr) -> 2 waves per SIMD; each wave owns 2 N-tiles
// (32 permuted gate cols = 8 units) x K=96 = 6 MFMAs.
// SOFTWARE-PIPELINED X-STAGE: the 2 x-chain MFMAs for step t+1 depend only on
// prefetched xb (not on h_t), so they issue at the END of step t, before the
// barrier -> they execute during barrier-wait slack, and the post-barrier
// chain shrinks to {ds_read -> 2 chained h-MFMAs -> epilogue}. ax0/ax1 carry
// bias + x-partial across the barrier.
// Per lane: ONE gate value. quad encodes (tile = quad&1, batch = quad>>1);
// DPP gathers the 4 gates within each aligned 4-lane group; one cell chain.
// ---------------------------------------------------------------------------
__global__ __launch_bounds__(512, 2) void lstm_main(
    const __hip_bfloat16* __restrict__ x, const __hip_bfloat16* __restrict__ Wc,
    const float* __restrict__ biasc, float* __restrict__ cfin) {
  __shared__ __align__(16) short Hbuf[2][2][72];  // [buf][batch parity][unit] bf16, pad 72

  const int tid = threadIdx.x, lane = tid & 63, wave = tid >> 6;
  const int quad = lane >> 4, l15 = lane & 15;
  const int g = lane & 3;
  const int tsel = quad & 1;       // which of my 2 N-tiles holds my gate col
  const int br = quad >> 1;        // which batch of the pair my lane handles
  const int unit = wave * 8 + tsel * 4 + (l15 >> 2);
  const int dir = (int)blockIdx.x & 1;
  const int pair = (int)blockIdx.x >> 1;
  const int b0 = pair * 2;
  const int bl = b0 + (l15 & 1);   // batch feeding my A-frag row

  // loop-invariant weight fragments (B-operand: lane = col, k = quad*8+j)
  bfrag8 wf[2][3];
  float bias[2];
#pragma unroll
  for (int tl = 0; tl < 2; ++tl) {
    const int np = wave * 32 + tl * 16 + l15;
    const __hip_bfloat16* wr = Wc + (size_t)(dir * 256 + np) * 96 + quad * 8;
#pragma unroll
    for (int kt = 0; kt < 3; ++kt) wf[tl][kt] = *(const bfrag8*)(wr + kt * 32);
    bias[tl] = biasc[dir * 256 + np];
  }
  // hoisted bias C-operand vectors (loop-invariant registers)
  const f32x4 bv0 = {bias[0], bias[0], bias[0], bias[0]};
  const f32x4 bv1 = {bias[1], bias[1], bias[1], bias[1]};

  // activation constants for my gate column (g==2 is the tanh gate)
  const bool isg = (g == 2);
  const float S = isg ? 2.8853900817779268f : -1.4426950408889634f;
  const float Aa = isg ? 1.0f : 0.0f;
  const float Bb = isg ? -2.0f : 1.0f;

  const __hip_bfloat16* xr = x + (size_t)bl * T_LEN * 32 + quad * 8;

  // h0 = 0 for both ping-pong buffers, both parities (288 shorts total)
  if (tid < 288) ((short*)Hbuf)[tid] = 0;

  bfrag8 xb[4];
#pragma unroll
  for (int qq = 0; qq < 4; ++qq) {  // prefetch x frags for t = 0..3
    int tp = dir ? (T_LEN - 1 - qq) : qq;
    xb[qq] = *(const bfrag8*)(xr + (size_t)tp * 32);
  }

  // prologue: x-stage for t=0 (bias-seeded)
  f32x4 ax0 = __builtin_amdgcn_mfma_f32_16x16x32_bf16(xb[0], wf[0][0], bv0, 0, 0, 0);
  f32x4 ax1 = __builtin_amdgcn_mfma_f32_16x16x32_bf16(xb[0], wf[1][0], bv1, 0, 0, 0);

  float cst = 0.f;
  wg_barrier();

#pragma unroll 4
  for (int t = 0; t < T_LEN; ++t) {
    const int cur = t & 1;
    // h A-frags: parity picked by my row's batch; addresses are 16B-aligned
    // broadcasts (8 distinct 16B lines covering 32 banks -> conflict-free).
    const short* hb = &Hbuf[cur][l15 & 1][0];
    bfrag8 ahA = *(const bfrag8*)(hb + quad * 8);       // units q*8..q*8+7
    bfrag8 ahB = *(const bfrag8*)(hb + 32 + quad * 8);  // units 32+q*8..
    // ---- h-stage MFMAs onto the x-partial computed at the end of step t-1
    f32x4 a0 = __builtin_amdgcn_mfma_f32_16x16x32_bf16(ahA, wf[0][1], ax0, 0, 0, 0);
    f32x4 a1 = __builtin_amdgcn_mfma_f32_16x16x32_bf16(ahA, wf[1][1], ax1, 0, 0, 0);
    a0 = __builtin_amdgcn_mfma_f32_16x16x32_bf16(ahB, wf[0][2], a0, 0, 0, 0);
    a1 = __builtin_amdgcn_mfma_f32_16x16x32_bf16(ahB, wf[1][2], a1, 0, 0, 0);
    {  // prefetch x frag for t+4 into xb[t&3] (its row-t content was consumed
       // by the x-stage at the end of step t-1; stays in flight across barrier)
      int tn = t + 4; if (tn > T_LEN - 1) tn = T_LEN - 1;
      int tp = dir ? (T_LEN - 1 - tn) : tn;
      xb[t & 3] = *(const bfrag8*)(xr + (size_t)tp * 32);
    }
    // ---- my gate value: tile = quad&1, acc reg = batch = quad>>1 ----
    float v0 = tsel ? a1[0] : a0[0];   // batch-0 candidate
    float v1 = tsel ? a1[1] : a0[1];   // batch-1 candidate
    float v = (quad & 2) ? v1 : v0;
    float act = fact(v, S, Aa, Bb);
    // gather the 4 gates of my unit from my aligned 4-lane group (i,f,g,o)
    float gi = qb<0>(act), gf = qb<1>(act), gg = qb<2>(act), go = qb<3>(act);
    cst = gf * cst + gi * gg;
    float h = go * ftanh(cst);
    if (g == 0) *(__hip_bfloat16*)&Hbuf[cur ^ 1][br][unit] = __float2bfloat16(h);
    // ---- x-stage for step t+1 (no h dependency): overlaps barrier wait.
    // xb[(t+1)&3] holds row t+1 (overwritten only at step t+1's prefetch).
    ax0 = __builtin_amdgcn_mfma_f32_16x16x32_bf16(xb[(t + 1) & 3], wf[0][0], bv0, 0, 0, 0);
    ax1 = __builtin_amdgcn_mfma_f32_16x16x32_bf16(xb[(t + 1) & 3], wf[1][0], bv1, 0, 0, 0);
    wg_barrier();
  }

  // reference quirk: final CELL states feed the FC
  if (g == 0) cfin[(size_t)(dir * 256 + b0 + br) * 64 + unit] = cst;
}

// ---------------------------------------------------------------------------
// Kernel 4: out[b,:] = [c_fwd(b) ; c_bwd(b)] @ W_fin^T + b_fin
// ---------------------------------------------------------------------------
__global__ void final_fc(const float* __restrict__ cfin,
                         const float* __restrict__ W_fin,
                         const float* __restrict__ b_fin,
                         float* __restrict__ out) {
  int b = threadIdx.x;  // 256 threads, 1 block
  const float* cf = cfin + (size_t)b * 64;
  const float* cb = cfin + (size_t)(256 + b) * 64;
  float a0 = b_fin[0], a1 = b_fin[1], a2 = b_fin[2];
  for (int u = 0; u < 64; ++u) {
    float vf = cf[u], vb = cb[u];
    a0 += W_fin[0 * 128 + u] * vf + W_fin[0 * 128 + 64 + u] * vb;
    a1 += W_fin[1 * 128 + u] * vf + W_fin[1 * 128 + 64 + u] * vb;
    a2 += W_fin[2 * 128 + u] * vf + W_fin[2 * 128 + 64 + u] * vb;
  }
  out[b * 3 + 0] = a0;
  out[b * 3 + 1] = a1;
  out[b * 3 + 2] = a2;
}

extern "C" void kernel_launch(void* const* d_in, const int* in_sizes, int n_in,
                              void* d_out, int out_size, void* d_ws, size_t ws_size,
                              hipStream_t stream) {
  (void)in_sizes; (void)n_in; (void)out_size; (void)ws_size;
  const float* c      = (const float*)d_in[0];
  const float* W_enc  = (const float*)d_in[1];
  const float* b_enc  = (const float*)d_in[2];
  const float* W_ih_f = (const float*)d_in[3];
  const float* W_hh_f = (const float*)d_in[4];
  const float* b_f    = (const float*)d_in[5];
  const float* W_ih_b = (const float*)d_in[6];
  const float* W_hh_b = (const float*)d_in[7];
  const float* b_b    = (const float*)d_in[8];
  const float* W_fin  = (const float*)d_in[9];
  const float* b_fin  = (const float*)d_in[10];
  float* out = (float*)d_out;

  char* ws = (char*)d_ws;
  __hip_bfloat16* x  = (__hip_bfloat16*)ws;                 // 64 MiB
  __hip_bfloat16* Wc = (__hip_bfloat16*)(ws + 67108864);    // 98304 B
  float* biasc       = (float*)(ws + 67108864 + 98304);     // 2048 B
  float* cfin        = (float*)(ws + 67108864 + 100352);    // 131072 B

  prep_weights<<<2, 256, 0, stream>>>(b_enc, W_ih_f, W_hh_f, b_f,
                                      W_ih_b, W_hh_b, b_b, Wc, biasc);
  encoder<<<16384, 256, 0, stream>>>(c, W_enc, x);
  lstm_main<<<256, 512, 0, stream>>>(x, Wc, biasc, cfin);
  final_fc<<<1, 256, 0, stream>>>(cfin, W_fin, b_fin, out);
}